// Round 2
// baseline (1173.757 us; speedup 1.0000x reference)
//
#include <hip/hip_runtime.h>
#include <hip/hip_bf16.h>

#define CCOLS 1000
#define CVEC  250          // 1000 / 4 float4s per row
#define NEG_INF (-3.402823466e38f)

__global__ void zero_out_kernel(float* out) {
    if (threadIdx.x == 0) out[0] = 0.0f;
}

// One wave (64 lanes) per row. Lane L owns float4 chunks {L, L+64, L+128, L+192}
// (the last only for L<58 since 250 chunks). All reductions are wave-level
// __shfl_xor butterflies: no LDS, no __syncthreads, 4 independent waves/block.
__global__ __launch_bounds__(256, 4)
void row_loss_kernel(const float* __restrict__ score,
                     const float* __restrict__ label,
                     float* __restrict__ out,
                     int nrows, float inv_b) {
    const int lane   = threadIdx.x & 63;
    const int wavesb = blockDim.x >> 6;
    const int gwave  = blockIdx.x * wavesb + (threadIdx.x >> 6);
    const int nwaves = gridDim.x * wavesb;

    float acc = 0.0f;

    for (int row = gwave; row < nrows; row += nwaves) {
        const float4* s4p = reinterpret_cast<const float4*>(score + (size_t)row * CCOLS);
        const float4* l4p = reinterpret_cast<const float4*>(label + (size_t)row * CCOLS);

        float4 s[4], l[4];
        #pragma unroll
        for (int k = 0; k < 4; ++k) {
            const int c = lane + 64 * k;
            if (c < CVEC) { s[k] = s4p[c]; l[k] = l4p[c]; }
            else {
                s[k] = make_float4(0.f, 0.f, 0.f, 0.f);
                l[k] = make_float4(NEG_INF, NEG_INF, NEG_INF, NEG_INF);
            }
        }

        // ---- (1) wave argmax of label, carrying score at that column ----
        float lv = NEG_INF; int li = 0x7fffffff; float sv = 0.0f;
        #pragma unroll
        for (int k = 0; k < 4; ++k) {
            const int c = lane + 64 * k;
            if (c < CVEC) {
                const int base = c * 4;
                const float lx[4] = { l[k].x, l[k].y, l[k].z, l[k].w };
                const float sx[4] = { s[k].x, s[k].y, s[k].z, s[k].w };
                #pragma unroll
                for (int j = 0; j < 4; ++j) {
                    // strict > with ascending index scan == argmax lowest-index tiebreak
                    if (lx[j] > lv) { lv = lx[j]; li = base + j; sv = sx[j]; }
                }
            }
        }
        #pragma unroll
        for (int off = 1; off < 64; off <<= 1) {
            const float olv = __shfl_xor(lv, off);
            const int   oli = __shfl_xor(li, off);
            const float osv = __shfl_xor(sv, off);
            if (olv > lv || (olv == lv && oli < li)) { lv = olv; li = oli; sv = osv; }
        }
        const int   idx = li;   // same in all lanes after butterfly
        const float s_y = sv;

        // ---- (2) wave max of score excluding true class ----
        float mx = NEG_INF;
        #pragma unroll
        for (int k = 0; k < 4; ++k) {
            const int c = lane + 64 * k;
            if (c < CVEC) {
                const int base = c * 4;
                const float sx[4] = { s[k].x, s[k].y, s[k].z, s[k].w };
                #pragma unroll
                for (int j = 0; j < 4; ++j)
                    if (base + j != idx) mx = fmaxf(mx, sx[j]);
            }
        }
        #pragma unroll
        for (int off = 1; off < 64; off <<= 1) mx = fmaxf(mx, __shfl_xor(mx, off));
        const float M = mx;

        // ---- (3) wave sum of exp(score - M) excluding true class ----
        float sum = 0.0f;
        #pragma unroll
        for (int k = 0; k < 4; ++k) {
            const int c = lane + 64 * k;
            if (c < CVEC) {
                const int base = c * 4;
                const float sx[4] = { s[k].x, s[k].y, s[k].z, s[k].w };
                #pragma unroll
                for (int j = 0; j < 4; ++j)
                    if (base + j != idx) sum += __expf(sx[j] - M);
            }
        }
        #pragma unroll
        for (int off = 1; off < 64; off <<= 1) sum += __shfl_xor(sum, off);

        // loss = (1 + M - s_y) + log(sum_{j != idx} exp(s_j - M))   [alph=tao=1]
        acc += (1.0f + M - s_y) + __logf(sum);
    }

    if (lane == 0) atomicAdd(out, acc * inv_b);
}

extern "C" void kernel_launch(void* const* d_in, const int* in_sizes, int n_in,
                              void* d_out, int out_size, void* d_ws, size_t ws_size,
                              hipStream_t stream) {
    (void)n_in; (void)d_ws; (void)ws_size; (void)out_size;
    const float* score = (const float*)d_in[0];
    const float* label = (const float*)d_in[1];
    float* out = (float*)d_out;

    const int nrows = in_sizes[0] / CCOLS;   // B = 131072
    const float inv_b = 1.0f / (float)nrows;

    zero_out_kernel<<<1, 64, 0, stream>>>(out);

    // 8192 blocks x 4 waves = 32768 waves; 4 rows per wave, 32768 atomics total.
    row_loss_kernel<<<8192, 256, 0, stream>>>(score, label, out, nrows, inv_b);
}